// Round 9
// baseline (473.382 us; speedup 1.0000x reference)
//
#include <hip/hip_runtime.h>
#include <math.h>

#define BB   64
#define HWP  1024
#define SS   512
#define DD   256
#define TAU_INV (1.0f/0.07f)
#define SIGMA   (1.0f/1024.0f)

typedef unsigned short us;
typedef __attribute__((ext_vector_type(8))) short short8v;
typedef __attribute__((ext_vector_type(8))) unsigned short ushort8v;
typedef __attribute__((ext_vector_type(4))) float floatx4;

__device__ __forceinline__ float bf2f(us u) {
    return __uint_as_float((unsigned)u << 16);
}
__device__ __forceinline__ us f2bf(float f) {
    unsigned u = __float_as_uint(f);
    u += 0x7FFFu + ((u >> 16) & 1u);
    return (us)(u >> 16);
}
__device__ __forceinline__ void split_bf(float v, us& h, us& l) {
    h = f2bf(v);
    l = f2bf(v - bf2f(h));
}

__global__ void zero_out_k(float* out) { if (threadIdx.x == 0) out[0] = 0.0f; }

// =====================  MFMA GEMM  =====================
// C[m,n] = sum_k A(m,k)*B(n,k). Tile 128 x NT (NT=128/256), BK=32,
// 16x16x32 bf16 MFMA. Split modes carry hi+lo bf16 (3 mfma/pair).
// R8: NT=256 halves duplicate A fetches; minmax fused into G4 epilogue
// (EPI=3); G8 epilogue (EPI=4) emits row/col LSE partials + diag and
// never materializes f_sim.
enum { OPM_F32_ROW = 0, OPM_F32_COL = 1, OPM_SPL_ROW = 2, OPM_SPL_COL = 3,
       OPM_B16_COL = 4, OPM_B16_ROW = 5, OPM_WGT_COL = 6 };
enum { OUT_F32 = 0, OUT_B16 = 1 };

#define LDSTRIDE 40

template<int MODE, int ROWS>
__device__ __forceinline__ void stage_tile(
    const char* p0, const char* p1, int ld, int row0, int k0,
    us* ldsH, us* ldsL, int tid,
    const float* wlo, const float* whi)
{
    #pragma unroll
    for (int rr = 0; rr < ROWS / 128; ++rr) {
        if constexpr (MODE == OPM_SPL_ROW) {
            const us* ph = (const us*)p0;
            const us* pl = (const us*)p1;
            const int i = rr * 128 + (tid >> 1), ko = (tid & 1) * 16;
            const long long g = (long long)(row0 + i) * ld + k0 + ko;
            *(ushort8v*)&ldsH[i * LDSTRIDE + ko]     = *(const ushort8v*)&ph[g];
            *(ushort8v*)&ldsH[i * LDSTRIDE + ko + 8] = *(const ushort8v*)&ph[g + 8];
            *(ushort8v*)&ldsL[i * LDSTRIDE + ko]     = *(const ushort8v*)&pl[g];
            *(ushort8v*)&ldsL[i * LDSTRIDE + ko + 8] = *(const ushort8v*)&pl[g + 8];
        } else if constexpr (MODE == OPM_B16_ROW) {
            const us* ph = (const us*)p0;
            const int i = rr * 128 + (tid >> 1), ko = (tid & 1) * 16;
            const long long g = (long long)(row0 + i) * ld + k0 + ko;
            *(ushort8v*)&ldsH[i * LDSTRIDE + ko]     = *(const ushort8v*)&ph[g];
            *(ushort8v*)&ldsH[i * LDSTRIDE + ko + 8] = *(const ushort8v*)&ph[g + 8];
        } else if constexpr (MODE == OPM_F32_ROW) {
            const float* pf = (const float*)p0;
            const int i = rr * 128 + (tid >> 1), ko = (tid & 1) * 16;
            const long long g = (long long)(row0 + i) * ld + k0 + ko;
            us h16[16], l16a[16];
            #pragma unroll
            for (int c = 0; c < 16; c += 4) {
                float4 v = *(const float4*)&pf[g + c];
                split_bf(v.x, h16[c+0], l16a[c+0]); split_bf(v.y, h16[c+1], l16a[c+1]);
                split_bf(v.z, h16[c+2], l16a[c+2]); split_bf(v.w, h16[c+3], l16a[c+3]);
            }
            *(ushort8v*)&ldsH[i * LDSTRIDE + ko]     = *(const ushort8v*)&h16[0];
            *(ushort8v*)&ldsH[i * LDSTRIDE + ko + 8] = *(const ushort8v*)&h16[8];
            *(ushort8v*)&ldsL[i * LDSTRIDE + ko]     = *(const ushort8v*)&l16a[0];
            *(ushort8v*)&ldsL[i * LDSTRIDE + ko + 8] = *(const ushort8v*)&l16a[8];
        } else if constexpr (MODE == OPM_F32_COL) {
            const float* pf = (const float*)p0;
            const int m = rr * 128 + (tid & 127), kh = (tid >> 7) * 16;
            const long long base = (long long)(k0 + kh) * ld + row0 + m;
            us vh[16], vl[16];
            #pragma unroll
            for (int kk = 0; kk < 16; ++kk)
                split_bf(pf[base + (long long)kk * ld], vh[kk], vl[kk]);
            *(ushort8v*)&ldsH[m * LDSTRIDE + kh]     = *(const ushort8v*)&vh[0];
            *(ushort8v*)&ldsH[m * LDSTRIDE + kh + 8] = *(const ushort8v*)&vh[8];
            *(ushort8v*)&ldsL[m * LDSTRIDE + kh]     = *(const ushort8v*)&vl[0];
            *(ushort8v*)&ldsL[m * LDSTRIDE + kh + 8] = *(const ushort8v*)&vl[8];
        } else if constexpr (MODE == OPM_B16_COL) {
            const us* ph = (const us*)p0;
            const int m = rr * 128 + (tid & 127), kh = (tid >> 7) * 16;
            const long long base = (long long)(k0 + kh) * ld + row0 + m;
            us v[16];
            #pragma unroll
            for (int kk = 0; kk < 16; ++kk)
                v[kk] = ph[base + (long long)kk * ld];
            *(ushort8v*)&ldsH[m * LDSTRIDE + kh]     = *(const ushort8v*)&v[0];
            *(ushort8v*)&ldsH[m * LDSTRIDE + kh + 8] = *(const ushort8v*)&v[8];
        } else if constexpr (MODE == OPM_WGT_COL) {
            const us* ph = (const us*)p0;
            const int m = rr * 128 + (tid & 127), kh = (tid >> 7) * 16;
            const float lo = wlo[row0 + m];
            const float inv = 1.0f / (whi[row0 + m] - lo + 1e-8f);
            const long long base = (long long)(k0 + kh) * ld + row0 + m;
            us v[16];
            #pragma unroll
            for (int kk = 0; kk < 16; ++kk) {
                const float w = (bf2f(ph[base + (long long)kk * ld]) - lo) * inv;
                v[kk] = (w < SIGMA) ? (us)0 : f2bf(w);
            }
            *(ushort8v*)&ldsH[m * LDSTRIDE + kh]     = *(const ushort8v*)&v[0];
            *(ushort8v*)&ldsH[m * LDSTRIDE + kh + 8] = *(const ushort8v*)&v[8];
        }
    }
}

template<int AMODE, int BMODE, int OMODE, int EPI, int NT>
__global__ __launch_bounds__(256) void mfma_gemm(
    const void* A0, const void* A1, const void* B0, const void* B1, void* C0,
    int M, int N, int K, int lda, int ldb, int ldc,
    long long sA, long long sB, long long sC,
    const float* __restrict__ bias, const float* __restrict__ invm,
    const float* __restrict__ invn, float scale,
    const float* __restrict__ wlo, const float* __restrict__ whi,
    float* __restrict__ aux0, float* __restrict__ aux1,
    float* __restrict__ aux2, float* __restrict__ aux3, float* __restrict__ aux4)
{
    constexpr bool ASPL = (AMODE <= OPM_SPL_COL);
    constexpr bool BSPL = (BMODE <= OPM_SPL_COL);
    constexpr int NF = NT / 16;
    __shared__ __align__(16) us Ah[128 * LDSTRIDE];
    __shared__ __align__(16) us Al[ASPL ? 128 * LDSTRIDE : 8];
    __shared__ __align__(16) us Bh[NT * LDSTRIDE];
    __shared__ __align__(16) us Bl[BSPL ? NT * LDSTRIDE : 8];
    __shared__ float redm[(EPI >= 3) ? 4 * NT : 1];
    __shared__ float reds[(EPI >= 3) ? 4 * NT : 1];

    const int tid = threadIdx.x;
    const int w = tid >> 6, lane = tid & 63;
    const int quad = lane >> 4, l16 = lane & 15;
    const int m0 = blockIdx.x * 128, n0 = blockIdx.y * NT;
    const int b = blockIdx.z;

    const char* Ab0 = (const char*)A0 + (long long)b * sA;
    const char* Ab1 = A1 ? (const char*)A1 + (long long)b * sA : nullptr;
    const char* Bb0 = (const char*)B0 + (long long)b * sB;
    const char* Bb1 = B1 ? (const char*)B1 + (long long)b * sB : nullptr;
    const float* wloA = wlo ? wlo + (long long)b * M : nullptr;
    const float* whiA = whi ? whi + (long long)b * M : nullptr;

    floatx4 acc[2][NF];
    #pragma unroll
    for (int mi = 0; mi < 2; ++mi)
        #pragma unroll
        for (int ni = 0; ni < NF; ++ni)
            acc[mi][ni] = (floatx4){0.f, 0.f, 0.f, 0.f};

    for (int k0 = 0; k0 < K; k0 += 32) {
        stage_tile<AMODE, 128>(Ab0, Ab1, lda, m0, k0, Ah, Al, tid, wloA, whiA);
        stage_tile<BMODE, NT>(Bb0, Bb1, ldb, n0, k0, Bh, Bl, tid, nullptr, nullptr);
        __syncthreads();

        short8v ah[2], al[2];
        #pragma unroll
        for (int mi = 0; mi < 2; ++mi) {
            const int r = (32 * w + 16 * mi + l16) * LDSTRIDE + quad * 8;
            ah[mi] = *(const short8v*)&Ah[r];
            if constexpr (ASPL) al[mi] = *(const short8v*)&Al[r];
        }
        #pragma unroll
        for (int ni = 0; ni < NF; ++ni) {
            const int rB = (16 * ni + l16) * LDSTRIDE + quad * 8;
            short8v bh = *(const short8v*)&Bh[rB];
            acc[0][ni] = __builtin_amdgcn_mfma_f32_16x16x32_bf16(ah[0], bh, acc[0][ni], 0, 0, 0);
            acc[1][ni] = __builtin_amdgcn_mfma_f32_16x16x32_bf16(ah[1], bh, acc[1][ni], 0, 0, 0);
            if constexpr (BSPL) {
                short8v bl = *(const short8v*)&Bl[rB];
                acc[0][ni] = __builtin_amdgcn_mfma_f32_16x16x32_bf16(ah[0], bl, acc[0][ni], 0, 0, 0);
                acc[1][ni] = __builtin_amdgcn_mfma_f32_16x16x32_bf16(ah[1], bl, acc[1][ni], 0, 0, 0);
            }
            if constexpr (ASPL) {
                acc[0][ni] = __builtin_amdgcn_mfma_f32_16x16x32_bf16(al[0], bh, acc[0][ni], 0, 0, 0);
                acc[1][ni] = __builtin_amdgcn_mfma_f32_16x16x32_bf16(al[1], bh, acc[1][ni], 0, 0, 0);
            }
        }
        __syncthreads();
    }

    if constexpr (EPI != 4) {
        char* Cb0 = (char*)C0 + (long long)b * sC;
        #pragma unroll
        for (int mi = 0; mi < 2; ++mi)
            #pragma unroll
            for (int ni = 0; ni < NF; ++ni)
                #pragma unroll
                for (int r = 0; r < 4; ++r) {
                    const int row = m0 + 32 * w + 16 * mi + quad * 4 + r;
                    const int col = n0 + 16 * ni + l16;
                    float v = acc[mi][ni][r];
                    if constexpr (EPI == 1) v += bias[col];
                    const long long idx = (long long)row * ldc + col;
                    if constexpr (OMODE == OUT_F32) ((float*)Cb0)[idx] = v;
                    else                            ((us*)Cb0)[idx] = f2bf(v);
                }
    }

    if constexpr (EPI == 3) {
        // per-column min/max of bf16-rounded stored values -> partials
        #pragma unroll
        for (int ni = 0; ni < NF; ++ni) {
            float lo = 1e30f, hi = -1e30f;
            #pragma unroll
            for (int mi = 0; mi < 2; ++mi)
                #pragma unroll
                for (int r = 0; r < 4; ++r) {
                    const float vr = bf2f(f2bf(acc[mi][ni][r]));
                    lo = fminf(lo, vr); hi = fmaxf(hi, vr);
                }
            lo = fminf(lo, __shfl_xor(lo, 16)); lo = fminf(lo, __shfl_xor(lo, 32));
            hi = fmaxf(hi, __shfl_xor(hi, 16)); hi = fmaxf(hi, __shfl_xor(hi, 32));
            if (quad == 0) {
                redm[w * NT + 16 * ni + l16] = lo;
                reds[w * NT + 16 * ni + l16] = hi;
            }
        }
        __syncthreads();
        if (tid < NT) {
            float lo = 1e30f, hi = -1e30f;
            #pragma unroll
            for (int w4 = 0; w4 < 4; ++w4) {
                lo = fminf(lo, redm[w4 * NT + tid]);
                hi = fmaxf(hi, reds[w4 * NT + tid]);
            }
            const long long o = ((long long)b * N + n0 + tid) * 8 + blockIdx.x;
            aux0[o] = lo; aux1[o] = hi;
        }
    }

    if constexpr (EPI == 4) {
        // f_sim never stored: emit row/col LSE partials + diagonal.
        float bn[NF];
        #pragma unroll
        for (int ni = 0; ni < NF; ++ni)
            bn[ni] = invn[(long long)b * N + n0 + 16 * ni + l16] * scale;
        float amv[8];
        #pragma unroll
        for (int mi = 0; mi < 2; ++mi)
            #pragma unroll
            for (int r = 0; r < 4; ++r)
                amv[mi * 4 + r] = invm[(long long)b * M + m0 + 32 * w + 16 * mi + quad * 4 + r];

        // row pass: lse over this block's NT cols, reduce across l16
        #pragma unroll
        for (int mi = 0; mi < 2; ++mi)
            #pragma unroll
            for (int r = 0; r < 4; ++r) {
                const int grow = m0 + 32 * w + 16 * mi + quad * 4 + r;
                float vv[NF];
                float rm = -1e30f;
                #pragma unroll
                for (int ni = 0; ni < NF; ++ni) {
                    const float v = acc[mi][ni][r] * amv[mi * 4 + r] * bn[ni];
                    vv[ni] = v;
                    rm = fmaxf(rm, v);
                    if (grow == n0 + 16 * ni + l16)
                        aux4[(long long)b * M + grow] = v;
                }
                #pragma unroll
                for (int o = 8; o > 0; o >>= 1) rm = fmaxf(rm, __shfl_xor(rm, o));
                float rs = 0.f;
                #pragma unroll
                for (int ni = 0; ni < NF; ++ni) rs += expf(vv[ni] - rm);
                #pragma unroll
                for (int o = 8; o > 0; o >>= 1) rs += __shfl_xor(rs, o);
                if (l16 == 0) {
                    const long long o = ((long long)b * M + grow) * 2 + blockIdx.y;
                    aux0[o] = rm; aux1[o] = rs;
                }
            }

        // col pass: lse over this block's 128 rows, reduce across quads + waves
        #pragma unroll
        for (int ni = 0; ni < NF; ++ni) {
            float va[8];
            float cm = -1e30f;
            #pragma unroll
            for (int mi = 0; mi < 2; ++mi)
                #pragma unroll
                for (int r = 0; r < 4; ++r) {
                    const float v = acc[mi][ni][r] * amv[mi * 4 + r] * bn[ni];
                    va[mi * 4 + r] = v;
                    cm = fmaxf(cm, v);
                }
            cm = fmaxf(cm, __shfl_xor(cm, 16));
            cm = fmaxf(cm, __shfl_xor(cm, 32));
            float cs = 0.f;
            #pragma unroll
            for (int j = 0; j < 8; ++j) cs += expf(va[j] - cm);
            cs += __shfl_xor(cs, 16);
            cs += __shfl_xor(cs, 32);
            if (quad == 0) {
                redm[w * NT + 16 * ni + l16] = cm;
                reds[w * NT + 16 * ni + l16] = cs;
            }
        }
        __syncthreads();
        if (tid < NT) {
            float m = -1e30f, s = 0.f;
            #pragma unroll
            for (int w4 = 0; w4 < 4; ++w4) {
                const float cm = redm[w4 * NT + tid], cs = reds[w4 * NT + tid];
                const float nm = fmaxf(m, cm);
                s = s * expf(m - nm) + cs * expf(cm - nm);
                m = nm;
            }
            const long long o = ((long long)b * N + n0 + tid) * 4 + blockIdx.x;
            aux2[o] = m; aux3[o] = s;
        }
    }
}

// =====================  small kernels  =====================

__global__ __launch_bounds__(256) void convert_w_k(
    const float* Wv, const float* Wt, us* Wvh, us* Wvl, us* Wth, us* Wtl)
{
    const int i = blockIdx.x * 256 + threadIdx.x;
    split_bf(Wv[i], Wvh[i], Wvl[i]);
    split_bf(Wt[i], Wth[i], Wtl[i]);
}

__global__ __launch_bounds__(256) void mean_img_k(
    const float* __restrict__ img, float* __restrict__ mimg)
{
    const int row = blockIdx.x * 4 + (threadIdx.x >> 6);
    const int lane = threadIdx.x & 63;
    const float* p = img + (long long)row * 1024;
    float s = 0.f;
    #pragma unroll
    for (int c = 0; c < 4; ++c) {
        float4 v = *(const float4*)&p[(c * 64 + lane) * 4];
        s += v.x + v.y + v.z + v.w;
    }
    #pragma unroll
    for (int o = 32; o > 0; o >>= 1) s += __shfl_xor(s, o);
    if (lane == 0) mimg[row] = s * (1.0f / 1024.0f);
}

__global__ __launch_bounds__(256) void mean_text_s1(
    const float* __restrict__ text, float* __restrict__ part)
{
    const int b = blockIdx.x, ch = blockIdx.y, k = threadIdx.x;
    const float* p = text + ((long long)b * 512 + ch * 64) * 256 + k;
    float s = 0.f;
    for (int r = 0; r < 64; ++r) s += p[r * 256];
    part[(b * 8 + ch) * 256 + k] = s;
}
__global__ __launch_bounds__(256) void mean_text_s2(
    const float* __restrict__ part, float* __restrict__ mt)
{
    const int b = blockIdx.x, k = threadIdx.x;
    float s = 0.f;
    for (int c = 0; c < 8; ++c) s += part[(b * 8 + c) * 256 + k];
    mt[b * 256 + k] = s * (1.0f / 512.0f);
}

__global__ __launch_bounds__(256) void small_adapter_k(
    const float* __restrict__ x, const float* __restrict__ W,
    const float* __restrict__ bias, float* __restrict__ y)
{
    const int b = blockIdx.x, d = threadIdx.x;
    __shared__ float xs[256];
    xs[d] = x[b * 256 + d];
    __syncthreads();
    const float* w = W + (long long)d * 256;
    float s = bias[d];
    for (int k = 0; k < 256; ++k) s += xs[k] * w[k];
    y[b * 256 + d] = s;
}

// ---- parallelized global loss ----

__global__ __launch_bounds__(256) void inv_norm_f32_k(
    const float* __restrict__ x, float* __restrict__ inv)
{
    const int row = blockIdx.x * 4 + (threadIdx.x >> 6);
    const int lane = threadIdx.x & 63;
    float4 v = *(const float4*)&x[(long long)row * 256 + lane * 4];
    float s = v.x * v.x + v.y * v.y + v.z * v.z + v.w * v.w;
    #pragma unroll
    for (int o = 32; o > 0; o >>= 1) s += __shfl_xor(s, o);
    if (lane == 0) inv[row] = 1.0f / fmaxf(sqrtf(s), 1e-8f);
}

__global__ __launch_bounds__(256) void g_sim_k(
    const float* __restrict__ gi, const float* __restrict__ gt,
    const float* __restrict__ invI, const float* __restrict__ invT,
    float* __restrict__ gs)
{
    const int i = blockIdx.x, t = threadIdx.x;
    const int j = t >> 2, part = t & 3;
    __shared__ float a[256];
    a[t] = gi[i * 256 + t];
    __syncthreads();
    const float* bp = gt + (long long)j * 256 + part * 64;
    const float* ap = a + part * 64;
    float s = 0.f;
    #pragma unroll 16
    for (int k = 0; k < 64; ++k) s += ap[k] * bp[k];
    s += __shfl_xor(s, 1);
    s += __shfl_xor(s, 2);
    if (part == 0) gs[i * 64 + j] = s * invI[i] * invT[j] * TAU_INV;
}

__global__ __launch_bounds__(64) void g_lse_k(
    const float* __restrict__ gs, float* __restrict__ out)
{
    const int b = blockIdx.x, lane = threadIdx.x;
    const bool is_col = b >= 64;
    const int r = is_col ? b - 64 : b;
    const float v = is_col ? gs[lane * 64 + r] : gs[r * 64 + lane];
    float m = v;
    #pragma unroll
    for (int o = 32; o > 0; o >>= 1) m = fmaxf(m, __shfl_xor(m, o));
    float s = expf(v - m);
    #pragma unroll
    for (int o = 32; o > 0; o >>= 1) s += __shfl_xor(s, o);
    if (lane == 0)
        atomicAdd(out, ((m + logf(s)) - gs[r * 64 + r]) * (0.5f / 64.0f));
}

// inv L2 norm of 256-wide single-bf16 rows
__global__ __launch_bounds__(256) void inv_norm_b16_k(
    const us* __restrict__ x, float* __restrict__ inv)
{
    const int row = blockIdx.x * 4 + (threadIdx.x >> 6);
    const int lane = threadIdx.x & 63;
    ushort4 h = *(const ushort4*)&x[(long long)row * 256 + lane * 4];
    const float x0 = bf2f(h.x), x1 = bf2f(h.y), x2 = bf2f(h.z), x3 = bf2f(h.w);
    float s = x0 * x0 + x1 * x1 + x2 * x2 + x3 * x3;
    #pragma unroll
    for (int o = 32; o > 0; o >>= 1) s += __shfl_xor(s, o);
    if (lane == 0) inv[row] = 1.0f / fmaxf(sqrtf(s), 1e-8f);
}

// ---- R8 merge kernels ----

// merge 8 minmax partials per (b,s); grid 128 x 256
__global__ __launch_bounds__(256) void minmax_merge_k(
    const float* __restrict__ mnp, const float* __restrict__ mxp,
    float* __restrict__ mn, float* __restrict__ mx)
{
    const int idx = blockIdx.x * 256 + threadIdx.x;
    float lo = 1e30f, hi = -1e30f;
    #pragma unroll
    for (int c = 0; c < 8; ++c) {
        lo = fminf(lo, mnp[(long long)idx * 8 + c]);
        hi = fmaxf(hi, mxp[(long long)idx * 8 + c]);
    }
    mn[idx] = lo; mx[idx] = hi;
}

// merge 2 row-LSE partials per (b,i), subtract diag; grid 128 x 256
__global__ __launch_bounds__(256) void fine_row_merge_k(
    const float* __restrict__ pm, const float* __restrict__ ps,
    const float* __restrict__ diag, float* __restrict__ out)
{
    const int idx = blockIdx.x * 256 + threadIdx.x;
    const float m0 = pm[(long long)idx * 2],     s0 = ps[(long long)idx * 2];
    const float m1 = pm[(long long)idx * 2 + 1], s1 = ps[(long long)idx * 2 + 1];
    const float nm = fmaxf(m0, m1);
    const float S = s0 * expf(m0 - nm) + s1 * expf(m1 - nm);
    const float contrib = (nm + logf(S)) - diag[idx];
    __shared__ float red[256];
    red[threadIdx.x] = contrib;
    __syncthreads();
    for (int w = 128; w > 0; w >>= 1) {
        if (threadIdx.x < w) red[threadIdx.x] += red[threadIdx.x + w];
        __syncthreads();
    }
    if (threadIdx.x == 0) atomicAdd(out, red[0] * (0.5f / (64.0f * 512.0f)));
}

// merge 4 col-LSE partials per (b,j), subtract diag; grid 128 x 256
__global__ __launch_bounds__(256) void fine_col_merge_k(
    const float* __restrict__ pm, const float* __restrict__ ps,
    const float* __restrict__ diag, float* __restrict__ out)
{
    const int idx = blockIdx.x * 256 + threadIdx.x;
    float m = -1e30f, s = 0.f;
    #pragma unroll
    for (int c = 0; c < 4; ++c) {
        const float cm = pm[(long long)idx * 4 + c], cs = ps[(long long)idx * 4 + c];
        const float nm = fmaxf(m, cm);
        s = s * expf(m - nm) + cs * expf(cm - nm);
        m = nm;
    }
    const float contrib = (m + logf(s)) - diag[idx];
    __shared__ float red[256];
    red[threadIdx.x] = contrib;
    __syncthreads();
    for (int w = 128; w > 0; w >>= 1) {
        if (threadIdx.x < w) red[threadIdx.x] += red[threadIdx.x + w];
        __syncthreads();
    }
    if (threadIdx.x == 0) atomicAdd(out, red[0] * (0.5f / (64.0f * 512.0f)));
}

extern "C" void kernel_launch(void* const* d_in, const int* in_sizes, int n_in,
                              void* d_out, int out_size, void* d_ws, size_t ws_size,
                              hipStream_t stream)
{
    const float* img  = (const float*)d_in[0];
    const float* text = (const float*)d_in[1];
    const float* Wv   = (const float*)d_in[2];
    const float* bv   = (const float*)d_in[3];
    const float* Wt   = (const float*)d_in[4];
    const float* bt   = (const float*)d_in[5];
    float* out = (float*)d_out;
    char* ws = (char*)d_ws;

    us* patches = (us*)(ws + 0);              // 33,554,432 B
    us* tokens  = (us*)(ws + 33554432);       // 16,777,216 B
    us* simW    = (us*)(ws + 50331648);       // 67,108,864 B
    us* lgve    = (us*)(ws + 117440512);      // 16,777,216 B
    char* st = ws + 134217728;
    float* mean_img  = (float*)(st + 0);
    float* mean_text = (float*)(st + 65536);
    float* mean_pat  = (float*)(st + 131072);
    float* mean_tok  = (float*)(st + 196608);
    float* g_img     = (float*)(st + 262144);
    float* g_txt     = (float*)(st + 327680);
    float* textpart  = (float*)(st + 393216);
    float* mnp       = (float*)(st + 917504);   // 1 MB
    float* mxp       = (float*)(st + 1966080);  // 1 MB
    float* mnv       = (float*)(st + 3014656);
    float* mxv       = (float*)(st + 3145728);
    float* inv_l     = (float*)(st + 3276800);
    float* inv_t     = (float*)(st + 3407872);
    us* Wvh = (us*)(st + 3538944);
    us* Wvl = (us*)(st + 3670016);
    us* Wth = (us*)(st + 3801088);
    us* Wtl = (us*)(st + 3932160);
    float* inv_gi  = (float*)(st + 4063232);
    float* inv_gt  = (float*)(st + 4063744);
    float* g_simbf = (float*)(st + 4064256);
    float* pm_row  = (float*)(st + 4194304);   // 256 KB
    float* ps_row  = (float*)(st + 4456448);   // 256 KB
    float* pm_col  = (float*)(st + 4718592);   // 512 KB
    float* ps_col  = (float*)(st + 5242880);   // 512 KB
    float* diag    = (float*)(st + 5767168);   // 128 KB

    zero_out_k<<<1, 64, 0, stream>>>(out);
    convert_w_k<<<256, 256, 0, stream>>>(Wv, Wt, Wvh, Wvl, Wth, Wtl);

    // Global path (mean commutes with linear)
    mean_img_k<<<4096, 256, 0, stream>>>(img, mean_img);
    mean_text_s1<<<dim3(64, 8), 256, 0, stream>>>(text, textpart);
    mean_text_s2<<<64, 256, 0, stream>>>(textpart, mean_text);
    small_adapter_k<<<BB, 256, 0, stream>>>(mean_img, Wv, bv, mean_pat);
    small_adapter_k<<<BB, 256, 0, stream>>>(mean_pat, Wv, bv, g_img);
    small_adapter_k<<<BB, 256, 0, stream>>>(mean_text, Wt, bt, mean_tok);
    small_adapter_k<<<BB, 256, 0, stream>>>(mean_tok, Wt, bt, g_txt);
    inv_norm_f32_k<<<16, 256, 0, stream>>>(g_img, inv_gi);
    inv_norm_f32_k<<<16, 256, 0, stream>>>(g_txt, inv_gt);
    g_sim_k<<<64, 256, 0, stream>>>(g_img, g_txt, inv_gi, inv_gt, g_simbf);
    g_lse_k<<<128, 64, 0, stream>>>(g_simbf, out);

    // G1: patches = img.Wv + bv (split internally, bf16 out; NT=256 -> img x1)
    mfma_gemm<OPM_F32_COL, OPM_SPL_ROW, OUT_B16, 1, 256><<<dim3(8, 1, BB), 256, 0, stream>>>(
        img, nullptr, Wvh, Wvl, patches,
        1024, 256, 256, 1024, 256, 256,
        1048576LL, 0LL, 524288LL, bv, nullptr, nullptr, 0.f, nullptr, nullptr,
        nullptr, nullptr, nullptr, nullptr, nullptr);

    // G2: tokens = text.Wt + bt
    mfma_gemm<OPM_F32_ROW, OPM_SPL_ROW, OUT_B16, 1, 256><<<dim3(4, 1, BB), 256, 0, stream>>>(
        text, nullptr, Wth, Wtl, tokens,
        512, 256, 256, 256, 256, 256,
        524288LL, 0LL, 262144LL, bt, nullptr, nullptr, 0.f, nullptr, nullptr,
        nullptr, nullptr, nullptr, nullptr, nullptr);

    // G4: sim = patches.tokens^T, minmax partials fused in epilogue
    mfma_gemm<OPM_B16_ROW, OPM_B16_ROW, OUT_B16, 3, 256><<<dim3(8, 2, BB), 256, 0, stream>>>(
        patches, nullptr, tokens, nullptr, simW,
        1024, 512, 256, 256, 256, 512,
        524288LL, 262144LL, 1048576LL, nullptr, nullptr, nullptr, 0.f, nullptr, nullptr,
        mnp, mxp, nullptr, nullptr, nullptr);

    minmax_merge_k<<<128, 256, 0, stream>>>(mnp, mxp, mnv, mxv);

    // G6: lgve = w.patches, weights transform fused into A staging (NT=256 -> sim x1)
    mfma_gemm<OPM_WGT_COL, OPM_B16_COL, OUT_B16, 0, 256><<<dim3(4, 1, BB), 256, 0, stream>>>(
        simW, nullptr, patches, nullptr, lgve,
        512, 256, 1024, 512, 256, 256,
        1048576LL, 524288LL, 262144LL, nullptr, nullptr, nullptr, 0.f, mnv, mxv,
        nullptr, nullptr, nullptr, nullptr, nullptr);

    inv_norm_b16_k<<<8192, 256, 0, stream>>>(lgve, inv_l);
    inv_norm_b16_k<<<8192, 256, 0, stream>>>(tokens, inv_t);

    // G8: f_sim never materialized -> row/col LSE partials + diag in epilogue
    mfma_gemm<OPM_B16_ROW, OPM_B16_ROW, OUT_B16, 4, 256><<<dim3(4, 2, BB), 256, 0, stream>>>(
        lgve, nullptr, tokens, nullptr, nullptr,
        512, 512, 256, 256, 256, 512,
        262144LL, 262144LL, 0LL, nullptr, inv_l, inv_t, TAU_INV, nullptr, nullptr,
        pm_row, ps_row, pm_col, ps_col, diag);

    fine_row_merge_k<<<128, 256, 0, stream>>>(pm_row, ps_row, diag, out);
    fine_col_merge_k<<<128, 256, 0, stream>>>(pm_col, ps_col, diag, out);
}

// Round 10
// 417.324 us; speedup vs baseline: 1.1343x; 1.1343x over previous
//
#include <hip/hip_runtime.h>
#include <math.h>

#define BB   64
#define HWP  1024
#define SS   512
#define DD   256
#define TAU_INV (1.0f/0.07f)
#define SIGMA   (1.0f/1024.0f)

typedef unsigned short us;
typedef __attribute__((ext_vector_type(8))) short short8v;
typedef __attribute__((ext_vector_type(8))) unsigned short ushort8v;
typedef __attribute__((ext_vector_type(4))) float floatx4;

__device__ __forceinline__ float bf2f(us u) {
    return __uint_as_float((unsigned)u << 16);
}
__device__ __forceinline__ us f2bf(float f) {
    unsigned u = __float_as_uint(f);
    u += 0x7FFFu + ((u >> 16) & 1u);
    return (us)(u >> 16);
}
__device__ __forceinline__ void split_bf(float v, us& h, us& l) {
    h = f2bf(v);
    l = f2bf(v - bf2f(h));
}

__global__ void zero_out_k(float* out) { if (threadIdx.x == 0) out[0] = 0.0f; }

// =====================  MFMA GEMM  =====================
// C[m,n] = sum_k A(m,k)*B(n,k). Tile 128 x NT, BK=32, 16x16x32 bf16 MFMA.
// R10: NT=128 on the fused/accumulate-heavy GEMMs (G4/G6/G8) — NT=256 there
// cost 128 acc VGPRs -> occupancy 10% -> HBM 2.1 TB/s (R9 regression).
// NT=256 kept only on G1/G2 (adapter GEMMs, small B, never in top-5).
enum { OPM_F32_ROW = 0, OPM_F32_COL = 1, OPM_SPL_ROW = 2, OPM_SPL_COL = 3,
       OPM_B16_COL = 4, OPM_B16_ROW = 5, OPM_WGT_COL = 6 };
enum { OUT_F32 = 0, OUT_B16 = 1 };

#define LDSTRIDE 40

template<int MODE, int ROWS>
__device__ __forceinline__ void stage_tile(
    const char* p0, const char* p1, int ld, int row0, int k0,
    us* ldsH, us* ldsL, int tid,
    const float* wlo, const float* whi)
{
    #pragma unroll
    for (int rr = 0; rr < ROWS / 128; ++rr) {
        if constexpr (MODE == OPM_SPL_ROW) {
            const us* ph = (const us*)p0;
            const us* pl = (const us*)p1;
            const int i = rr * 128 + (tid >> 1), ko = (tid & 1) * 16;
            const long long g = (long long)(row0 + i) * ld + k0 + ko;
            *(ushort8v*)&ldsH[i * LDSTRIDE + ko]     = *(const ushort8v*)&ph[g];
            *(ushort8v*)&ldsH[i * LDSTRIDE + ko + 8] = *(const ushort8v*)&ph[g + 8];
            *(ushort8v*)&ldsL[i * LDSTRIDE + ko]     = *(const ushort8v*)&pl[g];
            *(ushort8v*)&ldsL[i * LDSTRIDE + ko + 8] = *(const ushort8v*)&pl[g + 8];
        } else if constexpr (MODE == OPM_B16_ROW) {
            const us* ph = (const us*)p0;
            const int i = rr * 128 + (tid >> 1), ko = (tid & 1) * 16;
            const long long g = (long long)(row0 + i) * ld + k0 + ko;
            *(ushort8v*)&ldsH[i * LDSTRIDE + ko]     = *(const ushort8v*)&ph[g];
            *(ushort8v*)&ldsH[i * LDSTRIDE + ko + 8] = *(const ushort8v*)&ph[g + 8];
        } else if constexpr (MODE == OPM_F32_ROW) {
            const float* pf = (const float*)p0;
            const int i = rr * 128 + (tid >> 1), ko = (tid & 1) * 16;
            const long long g = (long long)(row0 + i) * ld + k0 + ko;
            us h16[16], l16a[16];
            #pragma unroll
            for (int c = 0; c < 16; c += 4) {
                float4 v = *(const float4*)&pf[g + c];
                split_bf(v.x, h16[c+0], l16a[c+0]); split_bf(v.y, h16[c+1], l16a[c+1]);
                split_bf(v.z, h16[c+2], l16a[c+2]); split_bf(v.w, h16[c+3], l16a[c+3]);
            }
            *(ushort8v*)&ldsH[i * LDSTRIDE + ko]     = *(const ushort8v*)&h16[0];
            *(ushort8v*)&ldsH[i * LDSTRIDE + ko + 8] = *(const ushort8v*)&h16[8];
            *(ushort8v*)&ldsL[i * LDSTRIDE + ko]     = *(const ushort8v*)&l16a[0];
            *(ushort8v*)&ldsL[i * LDSTRIDE + ko + 8] = *(const ushort8v*)&l16a[8];
        } else if constexpr (MODE == OPM_F32_COL) {
            const float* pf = (const float*)p0;
            const int m = rr * 128 + (tid & 127), kh = (tid >> 7) * 16;
            const long long base = (long long)(k0 + kh) * ld + row0 + m;
            us vh[16], vl[16];
            #pragma unroll
            for (int kk = 0; kk < 16; ++kk)
                split_bf(pf[base + (long long)kk * ld], vh[kk], vl[kk]);
            *(ushort8v*)&ldsH[m * LDSTRIDE + kh]     = *(const ushort8v*)&vh[0];
            *(ushort8v*)&ldsH[m * LDSTRIDE + kh + 8] = *(const ushort8v*)&vh[8];
            *(ushort8v*)&ldsL[m * LDSTRIDE + kh]     = *(const ushort8v*)&vl[0];
            *(ushort8v*)&ldsL[m * LDSTRIDE + kh + 8] = *(const ushort8v*)&vl[8];
        } else if constexpr (MODE == OPM_B16_COL) {
            const us* ph = (const us*)p0;
            const int m = rr * 128 + (tid & 127), kh = (tid >> 7) * 16;
            const long long base = (long long)(k0 + kh) * ld + row0 + m;
            us v[16];
            #pragma unroll
            for (int kk = 0; kk < 16; ++kk)
                v[kk] = ph[base + (long long)kk * ld];
            *(ushort8v*)&ldsH[m * LDSTRIDE + kh]     = *(const ushort8v*)&v[0];
            *(ushort8v*)&ldsH[m * LDSTRIDE + kh + 8] = *(const ushort8v*)&v[8];
        } else if constexpr (MODE == OPM_WGT_COL) {
            const us* ph = (const us*)p0;
            const int m = rr * 128 + (tid & 127), kh = (tid >> 7) * 16;
            const float lo = wlo[row0 + m];
            const float inv = 1.0f / (whi[row0 + m] - lo + 1e-8f);
            const long long base = (long long)(k0 + kh) * ld + row0 + m;
            us v[16];
            #pragma unroll
            for (int kk = 0; kk < 16; ++kk) {
                const float w = (bf2f(ph[base + (long long)kk * ld]) - lo) * inv;
                v[kk] = (w < SIGMA) ? (us)0 : f2bf(w);
            }
            *(ushort8v*)&ldsH[m * LDSTRIDE + kh]     = *(const ushort8v*)&v[0];
            *(ushort8v*)&ldsH[m * LDSTRIDE + kh + 8] = *(const ushort8v*)&v[8];
        }
    }
}

template<int AMODE, int BMODE, int OMODE, int EPI, int NT>
__global__ __launch_bounds__(256) void mfma_gemm(
    const void* A0, const void* A1, const void* B0, const void* B1, void* C0,
    int M, int N, int K, int lda, int ldb, int ldc,
    long long sA, long long sB, long long sC,
    const float* __restrict__ bias, const float* __restrict__ invm,
    const float* __restrict__ invn, float scale,
    const float* __restrict__ wlo, const float* __restrict__ whi,
    float* __restrict__ aux0, float* __restrict__ aux1,
    float* __restrict__ aux2, float* __restrict__ aux3, float* __restrict__ aux4)
{
    constexpr bool ASPL = (AMODE <= OPM_SPL_COL);
    constexpr bool BSPL = (BMODE <= OPM_SPL_COL);
    constexpr int NF = NT / 16;
    __shared__ __align__(16) us Ah[128 * LDSTRIDE];
    __shared__ __align__(16) us Al[ASPL ? 128 * LDSTRIDE : 8];
    __shared__ __align__(16) us Bh[NT * LDSTRIDE];
    __shared__ __align__(16) us Bl[BSPL ? NT * LDSTRIDE : 8];
    __shared__ float redm[(EPI >= 3) ? 4 * NT : 1];
    __shared__ float reds[(EPI >= 3) ? 4 * NT : 1];

    const int tid = threadIdx.x;
    const int w = tid >> 6, lane = tid & 63;
    const int quad = lane >> 4, l16 = lane & 15;
    const int m0 = blockIdx.x * 128, n0 = blockIdx.y * NT;
    const int b = blockIdx.z;

    const char* Ab0 = (const char*)A0 + (long long)b * sA;
    const char* Ab1 = A1 ? (const char*)A1 + (long long)b * sA : nullptr;
    const char* Bb0 = (const char*)B0 + (long long)b * sB;
    const char* Bb1 = B1 ? (const char*)B1 + (long long)b * sB : nullptr;
    const float* wloA = wlo ? wlo + (long long)b * M : nullptr;
    const float* whiA = whi ? whi + (long long)b * M : nullptr;

    floatx4 acc[2][NF];
    #pragma unroll
    for (int mi = 0; mi < 2; ++mi)
        #pragma unroll
        for (int ni = 0; ni < NF; ++ni)
            acc[mi][ni] = (floatx4){0.f, 0.f, 0.f, 0.f};

    for (int k0 = 0; k0 < K; k0 += 32) {
        stage_tile<AMODE, 128>(Ab0, Ab1, lda, m0, k0, Ah, Al, tid, wloA, whiA);
        stage_tile<BMODE, NT>(Bb0, Bb1, ldb, n0, k0, Bh, Bl, tid, nullptr, nullptr);
        __syncthreads();

        short8v ah[2], al[2];
        #pragma unroll
        for (int mi = 0; mi < 2; ++mi) {
            const int r = (32 * w + 16 * mi + l16) * LDSTRIDE + quad * 8;
            ah[mi] = *(const short8v*)&Ah[r];
            if constexpr (ASPL) al[mi] = *(const short8v*)&Al[r];
        }
        #pragma unroll
        for (int ni = 0; ni < NF; ++ni) {
            const int rB = (16 * ni + l16) * LDSTRIDE + quad * 8;
            short8v bh = *(const short8v*)&Bh[rB];
            acc[0][ni] = __builtin_amdgcn_mfma_f32_16x16x32_bf16(ah[0], bh, acc[0][ni], 0, 0, 0);
            acc[1][ni] = __builtin_amdgcn_mfma_f32_16x16x32_bf16(ah[1], bh, acc[1][ni], 0, 0, 0);
            if constexpr (BSPL) {
                short8v bl = *(const short8v*)&Bl[rB];
                acc[0][ni] = __builtin_amdgcn_mfma_f32_16x16x32_bf16(ah[0], bl, acc[0][ni], 0, 0, 0);
                acc[1][ni] = __builtin_amdgcn_mfma_f32_16x16x32_bf16(ah[1], bl, acc[1][ni], 0, 0, 0);
            }
            if constexpr (ASPL) {
                acc[0][ni] = __builtin_amdgcn_mfma_f32_16x16x32_bf16(al[0], bh, acc[0][ni], 0, 0, 0);
                acc[1][ni] = __builtin_amdgcn_mfma_f32_16x16x32_bf16(al[1], bh, acc[1][ni], 0, 0, 0);
            }
        }
        __syncthreads();
    }

    if constexpr (EPI != 4) {
        char* Cb0 = (char*)C0 + (long long)b * sC;
        #pragma unroll
        for (int mi = 0; mi < 2; ++mi)
            #pragma unroll
            for (int ni = 0; ni < NF; ++ni)
                #pragma unroll
                for (int r = 0; r < 4; ++r) {
                    const int row = m0 + 32 * w + 16 * mi + quad * 4 + r;
                    const int col = n0 + 16 * ni + l16;
                    float v = acc[mi][ni][r];
                    if constexpr (EPI == 1) v += bias[col];
                    const long long idx = (long long)row * ldc + col;
                    if constexpr (OMODE == OUT_F32) ((float*)Cb0)[idx] = v;
                    else                            ((us*)Cb0)[idx] = f2bf(v);
                }
    }

    if constexpr (EPI == 3) {
        // per-column min/max of bf16-rounded stored values -> 8 partials/(b,s)
        #pragma unroll
        for (int ni = 0; ni < NF; ++ni) {
            float lo = 1e30f, hi = -1e30f;
            #pragma unroll
            for (int mi = 0; mi < 2; ++mi)
                #pragma unroll
                for (int r = 0; r < 4; ++r) {
                    const float vr = bf2f(f2bf(acc[mi][ni][r]));
                    lo = fminf(lo, vr); hi = fmaxf(hi, vr);
                }
            lo = fminf(lo, __shfl_xor(lo, 16)); lo = fminf(lo, __shfl_xor(lo, 32));
            hi = fmaxf(hi, __shfl_xor(hi, 16)); hi = fmaxf(hi, __shfl_xor(hi, 32));
            if (quad == 0) {
                redm[w * NT + 16 * ni + l16] = lo;
                reds[w * NT + 16 * ni + l16] = hi;
            }
        }
        __syncthreads();
        if (tid < NT) {
            float lo = 1e30f, hi = -1e30f;
            #pragma unroll
            for (int w4 = 0; w4 < 4; ++w4) {
                lo = fminf(lo, redm[w4 * NT + tid]);
                hi = fmaxf(hi, reds[w4 * NT + tid]);
            }
            const long long o = ((long long)b * N + n0 + tid) * 8 + blockIdx.x;
            aux0[o] = lo; aux1[o] = hi;
        }
    }

    if constexpr (EPI == 4) {
        // f_sim never stored: emit row/col LSE partials + diagonal.
        float bn[NF];
        #pragma unroll
        for (int ni = 0; ni < NF; ++ni)
            bn[ni] = invn[(long long)b * N + n0 + 16 * ni + l16] * scale;
        float amv[8];
        #pragma unroll
        for (int mi = 0; mi < 2; ++mi)
            #pragma unroll
            for (int r = 0; r < 4; ++r)
                amv[mi * 4 + r] = invm[(long long)b * M + m0 + 32 * w + 16 * mi + quad * 4 + r];

        // row pass: lse over this block's NT cols, reduce across l16
        #pragma unroll
        for (int mi = 0; mi < 2; ++mi)
            #pragma unroll
            for (int r = 0; r < 4; ++r) {
                const int grow = m0 + 32 * w + 16 * mi + quad * 4 + r;
                float vv[NF];
                float rm = -1e30f;
                #pragma unroll
                for (int ni = 0; ni < NF; ++ni) {
                    const float v = acc[mi][ni][r] * amv[mi * 4 + r] * bn[ni];
                    vv[ni] = v;
                    rm = fmaxf(rm, v);
                    if (grow == n0 + 16 * ni + l16)
                        aux4[(long long)b * M + grow] = v;
                }
                #pragma unroll
                for (int o = 8; o > 0; o >>= 1) rm = fmaxf(rm, __shfl_xor(rm, o));
                float rs = 0.f;
                #pragma unroll
                for (int ni = 0; ni < NF; ++ni) rs += expf(vv[ni] - rm);
                #pragma unroll
                for (int o = 8; o > 0; o >>= 1) rs += __shfl_xor(rs, o);
                if (l16 == 0) {
                    const long long o = ((long long)b * M + grow) * 4 + blockIdx.y;
                    aux0[o] = rm; aux1[o] = rs;
                }
            }

        // col pass: lse over this block's 128 rows, reduce across quads + waves
        #pragma unroll
        for (int ni = 0; ni < NF; ++ni) {
            float va[8];
            float cm = -1e30f;
            #pragma unroll
            for (int mi = 0; mi < 2; ++mi)
                #pragma unroll
                for (int r = 0; r < 4; ++r) {
                    const float v = acc[mi][ni][r] * amv[mi * 4 + r] * bn[ni];
                    va[mi * 4 + r] = v;
                    cm = fmaxf(cm, v);
                }
            cm = fmaxf(cm, __shfl_xor(cm, 16));
            cm = fmaxf(cm, __shfl_xor(cm, 32));
            float cs = 0.f;
            #pragma unroll
            for (int j = 0; j < 8; ++j) cs += expf(va[j] - cm);
            cs += __shfl_xor(cs, 16);
            cs += __shfl_xor(cs, 32);
            if (quad == 0) {
                redm[w * NT + 16 * ni + l16] = cm;
                reds[w * NT + 16 * ni + l16] = cs;
            }
        }
        __syncthreads();
        if (tid < NT) {
            float m = -1e30f, s = 0.f;
            #pragma unroll
            for (int w4 = 0; w4 < 4; ++w4) {
                const float cm = redm[w4 * NT + tid], cs = reds[w4 * NT + tid];
                const float nm = fmaxf(m, cm);
                s = s * expf(m - nm) + cs * expf(cm - nm);
                m = nm;
            }
            const long long o = ((long long)b * N + n0 + tid) * 4 + blockIdx.x;
            aux2[o] = m; aux3[o] = s;
        }
    }
}

// =====================  small kernels  =====================

__global__ __launch_bounds__(256) void convert_w_k(
    const float* Wv, const float* Wt, us* Wvh, us* Wvl, us* Wth, us* Wtl)
{
    const int i = blockIdx.x * 256 + threadIdx.x;
    split_bf(Wv[i], Wvh[i], Wvl[i]);
    split_bf(Wt[i], Wth[i], Wtl[i]);
}

__global__ __launch_bounds__(256) void mean_img_k(
    const float* __restrict__ img, float* __restrict__ mimg)
{
    const int row = blockIdx.x * 4 + (threadIdx.x >> 6);
    const int lane = threadIdx.x & 63;
    const float* p = img + (long long)row * 1024;
    float s = 0.f;
    #pragma unroll
    for (int c = 0; c < 4; ++c) {
        float4 v = *(const float4*)&p[(c * 64 + lane) * 4];
        s += v.x + v.y + v.z + v.w;
    }
    #pragma unroll
    for (int o = 32; o > 0; o >>= 1) s += __shfl_xor(s, o);
    if (lane == 0) mimg[row] = s * (1.0f / 1024.0f);
}

__global__ __launch_bounds__(256) void mean_text_s1(
    const float* __restrict__ text, float* __restrict__ part)
{
    const int b = blockIdx.x, ch = blockIdx.y, k = threadIdx.x;
    const float* p = text + ((long long)b * 512 + ch * 64) * 256 + k;
    float s = 0.f;
    for (int r = 0; r < 64; ++r) s += p[r * 256];
    part[(b * 8 + ch) * 256 + k] = s;
}
__global__ __launch_bounds__(256) void mean_text_s2(
    const float* __restrict__ part, float* __restrict__ mt)
{
    const int b = blockIdx.x, k = threadIdx.x;
    float s = 0.f;
    for (int c = 0; c < 8; ++c) s += part[(b * 8 + c) * 256 + k];
    mt[b * 256 + k] = s * (1.0f / 512.0f);
}

__global__ __launch_bounds__(256) void small_adapter_k(
    const float* __restrict__ x, const float* __restrict__ W,
    const float* __restrict__ bias, float* __restrict__ y)
{
    const int b = blockIdx.x, d = threadIdx.x;
    __shared__ float xs[256];
    xs[d] = x[b * 256 + d];
    __syncthreads();
    const float* w = W + (long long)d * 256;
    float s = bias[d];
    for (int k = 0; k < 256; ++k) s += xs[k] * w[k];
    y[b * 256 + d] = s;
}

// ---- parallelized global loss ----

__global__ __launch_bounds__(256) void inv_norm_f32_k(
    const float* __restrict__ x, float* __restrict__ inv)
{
    const int row = blockIdx.x * 4 + (threadIdx.x >> 6);
    const int lane = threadIdx.x & 63;
    float4 v = *(const float4*)&x[(long long)row * 256 + lane * 4];
    float s = v.x * v.x + v.y * v.y + v.z * v.z + v.w * v.w;
    #pragma unroll
    for (int o = 32; o > 0; o >>= 1) s += __shfl_xor(s, o);
    if (lane == 0) inv[row] = 1.0f / fmaxf(sqrtf(s), 1e-8f);
}

__global__ __launch_bounds__(256) void g_sim_k(
    const float* __restrict__ gi, const float* __restrict__ gt,
    const float* __restrict__ invI, const float* __restrict__ invT,
    float* __restrict__ gs)
{
    const int i = blockIdx.x, t = threadIdx.x;
    const int j = t >> 2, part = t & 3;
    __shared__ float a[256];
    a[t] = gi[i * 256 + t];
    __syncthreads();
    const float* bp = gt + (long long)j * 256 + part * 64;
    const float* ap = a + part * 64;
    float s = 0.f;
    #pragma unroll 16
    for (int k = 0; k < 64; ++k) s += ap[k] * bp[k];
    s += __shfl_xor(s, 1);
    s += __shfl_xor(s, 2);
    if (part == 0) gs[i * 64 + j] = s * invI[i] * invT[j] * TAU_INV;
}

__global__ __launch_bounds__(64) void g_lse_k(
    const float* __restrict__ gs, float* __restrict__ out)
{
    const int b = blockIdx.x, lane = threadIdx.x;
    const bool is_col = b >= 64;
    const int r = is_col ? b - 64 : b;
    const float v = is_col ? gs[lane * 64 + r] : gs[r * 64 + lane];
    float m = v;
    #pragma unroll
    for (int o = 32; o > 0; o >>= 1) m = fmaxf(m, __shfl_xor(m, o));
    float s = expf(v - m);
    #pragma unroll
    for (int o = 32; o > 0; o >>= 1) s += __shfl_xor(s, o);
    if (lane == 0)
        atomicAdd(out, ((m + logf(s)) - gs[r * 64 + r]) * (0.5f / 64.0f));
}

// inv L2 norm of 256-wide single-bf16 rows
__global__ __launch_bounds__(256) void inv_norm_b16_k(
    const us* __restrict__ x, float* __restrict__ inv)
{
    const int row = blockIdx.x * 4 + (threadIdx.x >> 6);
    const int lane = threadIdx.x & 63;
    ushort4 h = *(const ushort4*)&x[(long long)row * 256 + lane * 4];
    const float x0 = bf2f(h.x), x1 = bf2f(h.y), x2 = bf2f(h.z), x3 = bf2f(h.w);
    float s = x0 * x0 + x1 * x1 + x2 * x2 + x3 * x3;
    #pragma unroll
    for (int o = 32; o > 0; o >>= 1) s += __shfl_xor(s, o);
    if (lane == 0) inv[row] = 1.0f / fmaxf(sqrtf(s), 1e-8f);
}

// ---- merge kernels ----

// merge 8 minmax partials per (b,s); grid 128 x 256
__global__ __launch_bounds__(256) void minmax_merge_k(
    const float* __restrict__ mnp, const float* __restrict__ mxp,
    float* __restrict__ mn, float* __restrict__ mx)
{
    const int idx = blockIdx.x * 256 + threadIdx.x;
    float lo = 1e30f, hi = -1e30f;
    #pragma unroll
    for (int c = 0; c < 8; ++c) {
        lo = fminf(lo, mnp[(long long)idx * 8 + c]);
        hi = fmaxf(hi, mxp[(long long)idx * 8 + c]);
    }
    mn[idx] = lo; mx[idx] = hi;
}

// merge 4 LSE partials per row/col, subtract diag; grid 128 x 256
__global__ __launch_bounds__(256) void fine_merge4_k(
    const float* __restrict__ pm, const float* __restrict__ ps,
    const float* __restrict__ diag, float* __restrict__ out)
{
    const int idx = blockIdx.x * 256 + threadIdx.x;
    float m = -1e30f, s = 0.f;
    #pragma unroll
    for (int c = 0; c < 4; ++c) {
        const float cm = pm[(long long)idx * 4 + c], cs = ps[(long long)idx * 4 + c];
        const float nm = fmaxf(m, cm);
        s = s * expf(m - nm) + cs * expf(cm - nm);
        m = nm;
    }
    const float contrib = (m + logf(s)) - diag[idx];
    __shared__ float red[256];
    red[threadIdx.x] = contrib;
    __syncthreads();
    for (int w = 128; w > 0; w >>= 1) {
        if (threadIdx.x < w) red[threadIdx.x] += red[threadIdx.x + w];
        __syncthreads();
    }
    if (threadIdx.x == 0) atomicAdd(out, red[0] * (0.5f / (64.0f * 512.0f)));
}

extern "C" void kernel_launch(void* const* d_in, const int* in_sizes, int n_in,
                              void* d_out, int out_size, void* d_ws, size_t ws_size,
                              hipStream_t stream)
{
    const float* img  = (const float*)d_in[0];
    const float* text = (const float*)d_in[1];
    const float* Wv   = (const float*)d_in[2];
    const float* bv   = (const float*)d_in[3];
    const float* Wt   = (const float*)d_in[4];
    const float* bt   = (const float*)d_in[5];
    float* out = (float*)d_out;
    char* ws = (char*)d_ws;

    us* patches = (us*)(ws + 0);              // 33,554,432 B
    us* tokens  = (us*)(ws + 33554432);       // 16,777,216 B
    us* simW    = (us*)(ws + 50331648);       // 67,108,864 B
    us* lgve    = (us*)(ws + 117440512);      // 16,777,216 B
    char* st = ws + 134217728;
    float* mean_img  = (float*)(st + 0);
    float* mean_text = (float*)(st + 65536);
    float* mean_pat  = (float*)(st + 131072);
    float* mean_tok  = (float*)(st + 196608);
    float* g_img     = (float*)(st + 262144);
    float* g_txt     = (float*)(st + 327680);
    float* textpart  = (float*)(st + 393216);
    float* mnp       = (float*)(st + 917504);   // 1 MB
    float* mxp       = (float*)(st + 1966080);  // 1 MB
    float* mnv       = (float*)(st + 3014656);
    float* mxv       = (float*)(st + 3145728);
    float* inv_l     = (float*)(st + 3276800);
    float* inv_t     = (float*)(st + 3407872);
    us* Wvh = (us*)(st + 3538944);
    us* Wvl = (us*)(st + 3670016);
    us* Wth = (us*)(st + 3801088);
    us* Wtl = (us*)(st + 3932160);
    float* inv_gi  = (float*)(st + 4063232);
    float* inv_gt  = (float*)(st + 4063744);
    float* g_simbf = (float*)(st + 4064256);
    float* pm_row  = (float*)(st + 4194304);   // 512 KB (4 partials/row)
    float* ps_row  = (float*)(st + 4718592);   // 512 KB
    float* pm_col  = (float*)(st + 5242880);   // 512 KB
    float* ps_col  = (float*)(st + 5767168);   // 512 KB
    float* diag    = (float*)(st + 6291456);   // 128 KB

    zero_out_k<<<1, 64, 0, stream>>>(out);
    convert_w_k<<<256, 256, 0, stream>>>(Wv, Wt, Wvh, Wvl, Wth, Wtl);

    // Global path (mean commutes with linear)
    mean_img_k<<<4096, 256, 0, stream>>>(img, mean_img);
    mean_text_s1<<<dim3(64, 8), 256, 0, stream>>>(text, textpart);
    mean_text_s2<<<64, 256, 0, stream>>>(textpart, mean_text);
    small_adapter_k<<<BB, 256, 0, stream>>>(mean_img, Wv, bv, mean_pat);
    small_adapter_k<<<BB, 256, 0, stream>>>(mean_pat, Wv, bv, g_img);
    small_adapter_k<<<BB, 256, 0, stream>>>(mean_text, Wt, bt, mean_tok);
    small_adapter_k<<<BB, 256, 0, stream>>>(mean_tok, Wt, bt, g_txt);
    inv_norm_f32_k<<<16, 256, 0, stream>>>(g_img, inv_gi);
    inv_norm_f32_k<<<16, 256, 0, stream>>>(g_txt, inv_gt);
    g_sim_k<<<64, 256, 0, stream>>>(g_img, g_txt, inv_gi, inv_gt, g_simbf);
    g_lse_k<<<128, 64, 0, stream>>>(g_simbf, out);

    // G1: patches = img.Wv + bv (split internally, bf16 out; NT=256 -> img x1)
    mfma_gemm<OPM_F32_COL, OPM_SPL_ROW, OUT_B16, 1, 256><<<dim3(8, 1, BB), 256, 0, stream>>>(
        img, nullptr, Wvh, Wvl, patches,
        1024, 256, 256, 1024, 256, 256,
        1048576LL, 0LL, 524288LL, bv, nullptr, nullptr, 0.f, nullptr, nullptr,
        nullptr, nullptr, nullptr, nullptr, nullptr);

    // G2: tokens = text.Wt + bt
    mfma_gemm<OPM_F32_ROW, OPM_SPL_ROW, OUT_B16, 1, 256><<<dim3(4, 1, BB), 256, 0, stream>>>(
        text, nullptr, Wth, Wtl, tokens,
        512, 256, 256, 256, 256, 256,
        524288LL, 0LL, 262144LL, bt, nullptr, nullptr, 0.f, nullptr, nullptr,
        nullptr, nullptr, nullptr, nullptr, nullptr);

    // G4: sim = patches.tokens^T, minmax fused; NT=128 restores occupancy
    mfma_gemm<OPM_B16_ROW, OPM_B16_ROW, OUT_B16, 3, 128><<<dim3(8, 4, BB), 256, 0, stream>>>(
        patches, nullptr, tokens, nullptr, simW,
        1024, 512, 256, 256, 256, 512,
        524288LL, 262144LL, 1048576LL, nullptr, nullptr, nullptr, 0.f, nullptr, nullptr,
        mnp, mxp, nullptr, nullptr, nullptr);

    minmax_merge_k<<<128, 256, 0, stream>>>(mnp, mxp, mnv, mxv);

    // G6: lgve = w.patches, weights fused into A staging; NT=128 (R8's 53us config)
    mfma_gemm<OPM_WGT_COL, OPM_B16_COL, OUT_B16, 0, 128><<<dim3(4, 2, BB), 256, 0, stream>>>(
        simW, nullptr, patches, nullptr, lgve,
        512, 256, 1024, 512, 256, 256,
        1048576LL, 524288LL, 262144LL, nullptr, nullptr, nullptr, 0.f, mnv, mxv,
        nullptr, nullptr, nullptr, nullptr, nullptr);

    inv_norm_b16_k<<<8192, 256, 0, stream>>>(lgve, inv_l);
    inv_norm_b16_k<<<8192, 256, 0, stream>>>(tokens, inv_t);

    // G8: f_sim never materialized; NT=128, 4 row partials + 4 col partials
    mfma_gemm<OPM_B16_ROW, OPM_B16_ROW, OUT_B16, 4, 128><<<dim3(4, 4, BB), 256, 0, stream>>>(
        lgve, nullptr, tokens, nullptr, nullptr,
        512, 512, 256, 256, 256, 512,
        262144LL, 262144LL, 0LL, nullptr, inv_l, inv_t, TAU_INV, nullptr, nullptr,
        pm_row, ps_row, pm_col, ps_col, diag);

    fine_merge4_k<<<128, 256, 0, stream>>>(pm_row, ps_row, diag, out);
    fine_merge4_k<<<128, 256, 0, stream>>>(pm_col, ps_col, diag, out);
}